// Round 1
// baseline (664.206 us; speedup 1.0000x reference)
//
#include <hip/hip_runtime.h>

// Segment sum: feat [N_NODES, 128] f32, sorted segment_ids [N_NODES] i32,
// out [NUM_SEGS, 128] f32. One block per segment; contiguous coalesced
// float4 streaming; LDS tree-reduce of the 8 row-partials.

#define D_FEAT 128
#define D4     32   // float4 per row

__device__ __forceinline__ float4 f4add(float4 a, float4 b) {
    a.x += b.x; a.y += b.y; a.z += b.z; a.w += b.w;
    return a;
}

__global__ __launch_bounds__(256) void SumNode_11905649344609_kernel(
        const float* __restrict__ feat,
        const int* __restrict__ ids,
        float* __restrict__ out,
        int n_nodes) {
    const int seg = blockIdx.x;

    // lower_bound(ids, seg): first index with ids[i] >= seg.
    // All threads compute redundantly (same addresses -> broadcast loads,
    // top levels L2/L3-resident across blocks). Uniform control flow.
    int lo = 0, hi = n_nodes;
    while (lo < hi) {
        int m = (lo + hi) >> 1;
        if (ids[m] < seg) lo = m + 1; else hi = m;
    }
    const int start = lo;
    // lower_bound(ids, seg+1), starting from `start` (ids sorted)
    hi = n_nodes;
    while (lo < hi) {
        int m = (lo + hi) >> 1;
        if (ids[m] <= seg) lo = m + 1; else hi = m;
    }
    const int end = lo;

    const int tid  = threadIdx.x;
    const int c4   = tid & (D4 - 1);   // float4 column slot 0..31
    const int roff = tid >> 5;         // row phase 0..7

    const float4* __restrict__ f4 = (const float4*)feat;
    float4 acc = make_float4(0.f, 0.f, 0.f, 0.f);

    // 8 rows in flight per block iteration; each lane loads 16 B coalesced.
    for (int r = start + roff; r < end; r += 8) {
        acc = f4add(acc, f4[(size_t)r * D4 + c4]);
    }

    // Reduce the 8 row-phase partials per column slot.
    __shared__ float4 sm[256];
    sm[tid] = acc;
    __syncthreads();
    if (tid < 128) sm[tid] = f4add(sm[tid], sm[tid + 128]);
    __syncthreads();
    if (tid < 64)  sm[tid] = f4add(sm[tid], sm[tid + 64]);
    __syncthreads();
    if (tid < 32) {
        float4 r = f4add(sm[tid], sm[tid + 32]);
        ((float4*)out)[(size_t)seg * D4 + tid] = r;
    }
}

extern "C" void kernel_launch(void* const* d_in, const int* in_sizes, int n_in,
                              void* d_out, int out_size, void* d_ws, size_t ws_size,
                              hipStream_t stream) {
    const float* feat = (const float*)d_in[0];
    const int*   ids  = (const int*)d_in[1];
    float*       out  = (float*)d_out;

    const int n_nodes  = in_sizes[1];          // 1,000,000
    const int num_segs = out_size / D_FEAT;    // 4096

    SumNode_11905649344609_kernel<<<num_segs, 256, 0, stream>>>(feat, ids, out, n_nodes);
}

// Round 2
// 629.076 us; speedup vs baseline: 1.0558x; 1.0558x over previous
//
#include <hip/hip_runtime.h>

// Segment sum: feat [N_NODES, 128] f32, sorted segment_ids [N_NODES] i32,
// out [NUM_SEGS, 128] f32. One block per segment; contiguous coalesced
// float4 streaming with 4x unroll (32 rows in flight / block, 4 outstanding
// wave-loads per wave); LDS tree-reduce of the 8 row-phase partials.

#define D_FEAT 128
#define D4     32   // float4 per row

typedef float f32x4 __attribute__((ext_vector_type(4)));

__global__ __launch_bounds__(256) void SumNode_11905649344609_kernel(
        const float* __restrict__ feat,
        const int* __restrict__ ids,
        float* __restrict__ out,
        int n_nodes) {
    const int seg = blockIdx.x;

    // lower_bound(ids, seg): first index with ids[i] >= seg.
    // Uniform across the block -> broadcast loads; ids (4 MB) stays
    // L2-resident because the feat stream below uses non-temporal loads.
    int lo = 0, hi = n_nodes;
    while (lo < hi) {
        int m = (lo + hi) >> 1;
        if (ids[m] < seg) lo = m + 1; else hi = m;
    }
    const int start = lo;
    hi = n_nodes;
    while (lo < hi) {
        int m = (lo + hi) >> 1;
        if (ids[m] <= seg) lo = m + 1; else hi = m;
    }
    const int end = lo;

    const int tid  = threadIdx.x;
    const int c4   = tid & (D4 - 1);   // float4 column slot 0..31
    const int roff = tid >> 5;         // row phase 0..7

    const f32x4* __restrict__ f4 = (const f32x4*)feat;

    f32x4 a0 = {0.f, 0.f, 0.f, 0.f};
    f32x4 a1 = a0, a2 = a0, a3 = a0;

    int r = start + roff;
    // Main loop: 32 rows per block-iteration, 4 independent loads per lane.
    for (; r + 24 < end; r += 32) {
        f32x4 v0 = __builtin_nontemporal_load(&f4[(size_t)(r)      * D4 + c4]);
        f32x4 v1 = __builtin_nontemporal_load(&f4[(size_t)(r +  8) * D4 + c4]);
        f32x4 v2 = __builtin_nontemporal_load(&f4[(size_t)(r + 16) * D4 + c4]);
        f32x4 v3 = __builtin_nontemporal_load(&f4[(size_t)(r + 24) * D4 + c4]);
        a0 += v0; a1 += v1; a2 += v2; a3 += v3;
    }
    // Remainder: 8 rows at a time.
    for (; r < end; r += 8) {
        a0 += __builtin_nontemporal_load(&f4[(size_t)r * D4 + c4]);
    }

    f32x4 acc = (a0 + a1) + (a2 + a3);

    // Reduce the 8 row-phase partials per column slot.
    __shared__ f32x4 sm[256];
    sm[tid] = acc;
    __syncthreads();
    if (tid < 128) sm[tid] += sm[tid + 128];
    __syncthreads();
    if (tid < 64)  sm[tid] += sm[tid + 64];
    __syncthreads();
    if (tid < 32) {
        f32x4 res = sm[tid] + sm[tid + 32];
        ((f32x4*)out)[(size_t)seg * D4 + tid] = res;
    }
}

extern "C" void kernel_launch(void* const* d_in, const int* in_sizes, int n_in,
                              void* d_out, int out_size, void* d_ws, size_t ws_size,
                              hipStream_t stream) {
    const float* feat = (const float*)d_in[0];
    const int*   ids  = (const int*)d_in[1];
    float*       out  = (float*)d_out;

    const int n_nodes  = in_sizes[1];          // 1,000,000
    const int num_segs = out_size / D_FEAT;    // 4096

    SumNode_11905649344609_kernel<<<num_segs, 256, 0, stream>>>(feat, ids, out, n_nodes);
}

// Round 3
// 614.880 us; speedup vs baseline: 1.0802x; 1.0231x over previous
//
#include <hip/hip_runtime.h>

// Segment sum: feat [N_NODES, 128] f32, sorted segment_ids [N_NODES] i32,
// out [NUM_SEGS, 128] f32.
// Pass 1: boundary-scan ids -> offsets[NUM_SEGS+1] in d_ws.
// Pass 2: one block per segment; start/end from offsets (2 uniform loads);
// contiguous coalesced float4 streaming, 4x unrolled (4 outstanding
// wave-loads), LDS tree-reduce of the 8 row-phase partials.

#define D_FEAT 128
#define D4     32   // float4 per row

typedef float f32x4 __attribute__((ext_vector_type(4)));

__global__ __launch_bounds__(256) void seg_offsets_kernel(
        const int* __restrict__ ids,
        int* __restrict__ offsets,
        int n_nodes, int num_segs) {
    int i = blockIdx.x * blockDim.x + threadIdx.x;
    if (i >= n_nodes) return;
    int cur  = ids[i];
    int prev = (i == 0) ? -1 : ids[i - 1];
    // offsets[s] = first index with ids[idx] >= s, for s in (prev, cur]
    for (int s = prev + 1; s <= cur; ++s) offsets[s] = i;
    if (i == n_nodes - 1) {
        for (int s = cur + 1; s <= num_segs; ++s) offsets[s] = n_nodes;
    }
}

__global__ __launch_bounds__(256) void SumNode_11905649344609_kernel(
        const float* __restrict__ feat,
        const int* __restrict__ offsets,
        float* __restrict__ out) {
    const int seg   = blockIdx.x;
    const int start = offsets[seg];       // uniform -> scalar load
    const int end   = offsets[seg + 1];

    const int tid  = threadIdx.x;
    const int c4   = tid & (D4 - 1);   // float4 column slot 0..31
    const int roff = tid >> 5;         // row phase 0..7

    const f32x4* __restrict__ f4 = (const f32x4*)feat;

    f32x4 a0 = {0.f, 0.f, 0.f, 0.f};
    f32x4 a1 = a0, a2 = a0, a3 = a0;

    int r = start + roff;
    // Main loop: 32 rows per block-iteration, 4 independent loads per lane.
    for (; r + 24 < end; r += 32) {
        f32x4 v0 = __builtin_nontemporal_load(&f4[(size_t)(r)      * D4 + c4]);
        f32x4 v1 = __builtin_nontemporal_load(&f4[(size_t)(r +  8) * D4 + c4]);
        f32x4 v2 = __builtin_nontemporal_load(&f4[(size_t)(r + 16) * D4 + c4]);
        f32x4 v3 = __builtin_nontemporal_load(&f4[(size_t)(r + 24) * D4 + c4]);
        a0 += v0; a1 += v1; a2 += v2; a3 += v3;
    }
    // Remainder: 8 rows at a time.
    for (; r < end; r += 8) {
        a0 += __builtin_nontemporal_load(&f4[(size_t)r * D4 + c4]);
    }

    f32x4 acc = (a0 + a1) + (a2 + a3);

    // Reduce the 8 row-phase partials per column slot.
    __shared__ f32x4 sm[256];
    sm[tid] = acc;
    __syncthreads();
    if (tid < 128) sm[tid] += sm[tid + 128];
    __syncthreads();
    if (tid < 64)  sm[tid] += sm[tid + 64];
    __syncthreads();
    if (tid < 32) {
        f32x4 res = sm[tid] + sm[tid + 32];
        ((f32x4*)out)[(size_t)seg * D4 + tid] = res;
    }
}

extern "C" void kernel_launch(void* const* d_in, const int* in_sizes, int n_in,
                              void* d_out, int out_size, void* d_ws, size_t ws_size,
                              hipStream_t stream) {
    const float* feat = (const float*)d_in[0];
    const int*   ids  = (const int*)d_in[1];
    float*       out  = (float*)d_out;

    const int n_nodes  = in_sizes[1];          // 1,000,000
    const int num_segs = out_size / D_FEAT;    // 4096

    int* offsets = (int*)d_ws;                 // num_segs+1 ints

    seg_offsets_kernel<<<(n_nodes + 255) / 256, 256, 0, stream>>>(
        ids, offsets, n_nodes, num_segs);
    SumNode_11905649344609_kernel<<<num_segs, 256, 0, stream>>>(feat, offsets, out);
}